// Round 13
// baseline (725.617 us; speedup 1.0000x reference)
//
#include <hip/hip_runtime.h>
#include <hip/hip_bf16.h>
#include <hip/hip_fp16.h>
#include <stdint.h>

#define NN 50000
#define NE 800000
#define HD 128
#define EPSN 1e-5f
#define CAP 1152000   // padded CSR capacity: NE + NN*7 rounded up

typedef __hip_bfloat16 bf16;

__device__ __forceinline__ float us2f(unsigned short u) { return __uint_as_float((uint32_t)u << 16); }
__device__ __forceinline__ ushort f2us(float f) {
    bf16 b = __float2bfloat16(f);
    return *reinterpret_cast<ushort*>(&b);
}
__device__ __forceinline__ ushort f2h(float f) {
    __half h = __float2half(f);
    return *reinterpret_cast<ushort*>(&h);
}
__device__ __forceinline__ float h2f(ushort u) {
    __half h = *reinterpret_cast<__half*>(&u);
    return __half2float(h);
}
__device__ __forceinline__ ushort4 f4toh4(float4 v) {
    ushort4 o;
    o.x = f2h(v.x); o.y = f2h(v.y); o.z = f2h(v.z); o.w = f2h(v.w);
    return o;
}
__device__ __forceinline__ float4 h4tof4(ushort4 v) {
    return make_float4(h2f(v.x), h2f(v.y), h2f(v.z), h2f(v.w));
}

// canonical fp32 parameter block offsets
#define O_X    0
#define O_CW   100000
#define O_CB   100256
#define O_LNG  100384
#define O_LNB  100512
#define O_BNG  100640
#define O_BNB  100768
#define O_W1   100896
#define O_B1   117280
#define O_W2   117408
#define O_B2   133792
#define O_W3   133920
#define O_B3   150304
#define O_F1W  150432
#define O_F1B  154528
#define O_F2W  154560
#define O_F2B  154624
#define O_TOT  154626

struct Ptrs { const void* p[17]; };

__device__ const int SEG_OFF[18] = {O_X, O_CW, O_CB, O_LNG, O_LNB, O_BNG, O_BNB,
                                    O_W1, O_B1, O_W2, O_B2, O_W3, O_B3,
                                    O_F1W, O_F1B, O_F2W, O_F2B, O_TOT};

// Edge accessor: isL=1 -> int64 storage (read low words), else int32.
__device__ __forceinline__ int eidx(const int* __restrict__ ei, int isL, int which, int e) {
    size_t base = (size_t)which * NE + e;
    return isL ? ei[2 * base] : ei[base];
}

// ------- canonicalize floats to fp32; self-detects bf16; block 0 publishes flags -------
__global__ void k_conv(Ptrs ptrs, const int* __restrict__ ei, const ushort* __restrict__ cw,
                       float* __restrict__ cp, int* __restrict__ flags) {
    int t = threadIdx.x;
    __shared__ int sb[4], sv[4];
    int bad = 0;
    if (t < 128) {
        float val = us2f(cw[2 * t]);           // low half if f32, real weight if bf16
        bad = !(fabsf(val) <= 1.0f);           // NaN/Inf -> bad
    }
    for (int o = 32; o; o >>= 1) bad |= __shfl_xor(bad, o);
    if ((t & 63) == 0) sb[t >> 6] = bad;
    __syncthreads();
    int isB = ((sb[0] | sb[1] | sb[2] | sb[3]) == 0) ? 1 : 0;
    if (blockIdx.x == 0) {
        int v = ei[2 * t + 1] | ei[1000000 + 2 * t + 1];   // int64 -> odd words all zero
        for (int o = 32; o; o >>= 1) v |= __shfl_xor(v, o);
        if ((t & 63) == 0) sv[t >> 6] = v;
        __syncthreads();
        if (t == 0) {
            flags[0] = ((sv[0] | sv[1] | sv[2] | sv[3]) == 0) ? 1 : 0;
            flags[1] = isB;
        }
    }
    int i = blockIdx.x * 256 + t;
    if (i >= O_TOT) return;
    int s = 0;
    while (i >= SEG_OFF[s + 1]) s++;
    int local = i - SEG_OFF[s];
    const void* src = ptrs.p[s];
    cp[i] = isB ? us2f(((const ushort*)src)[local]) : ((const float*)src)[local];
}

// ---------------- graph preprocessing (deg zeroed by memset; = edge-only count) ------

__global__ void k_deg(const int* __restrict__ ei, const int* __restrict__ flags,
                      int* __restrict__ deg) {
    int e = blockIdx.x * 256 + threadIdx.x;
    if (e < NE) atomicAdd(&deg[eidx(ei, flags[0], 1, e)], 1);
}

// wave-aggregated cursor: shfl prefix-scan of cpad, one atomic per wave.
__global__ void k_dinv_alloc(const int* __restrict__ deg, float* __restrict__ dinv,
                             int* __restrict__ startA, int* __restrict__ curA,
                             int* __restrict__ cursor, int2* __restrict__ srw) {
    int i = blockIdx.x * 256 + threadIdx.x;
    int lane = threadIdx.x & 63;
    int c = 0, cpad = 0;
    bool valid = (i < NN);
    if (valid) {
        c = deg[i];                        // edge-only in-count
        dinv[i] = rsqrtf((float)(c + 1));  // +1 self-loop
        cpad = (c + 7) & ~7;               // pad list to multiple of 8
    }
    int scan = cpad;                       // inclusive wave scan
    for (int o = 1; o < 64; o <<= 1) {
        int v = __shfl_up(scan, o);
        if (lane >= o) scan += v;
    }
    int tot = __shfl(scan, 63);
    int base = 0;
    if (lane == 0) base = atomicAdd(cursor, tot);
    base = __shfl(base, 0);
    int s = base + scan - cpad;            // exclusive offset
    if (valid) {
        startA[i] = s;
        curA[i] = s;
        for (int j = c; j < cpad; j++) srw[s + j] = make_int2(0, 0);  // sentinels w=0
    }
}

__global__ void k_fill(const int* __restrict__ ei, const int* __restrict__ flags,
                       const float* __restrict__ dinv, int* __restrict__ curA,
                       int2* __restrict__ srw) {
    int e = blockIdx.x * 256 + threadIdx.x;
    if (e >= NE) return;
    int isL = flags[0];
    int r = eidx(ei, isL, 0, e);
    int c = eidx(ei, isL, 1, e);
    int p = atomicAdd(&curA[c], 1);
    srw[p] = make_int2(r << 7, __float_as_int(dinv[r] * dinv[c]));
}

// ------- layer-0 GEMM fused with embed: u = LN(relu(x@cW+cb)); h=fp16(u); t0h=fp16(u@W) -------

__global__ __launch_bounds__(256) void k_gemm0(const float* __restrict__ cp,
                                               ushort* __restrict__ hh,
                                               const float* __restrict__ Wf,
                                               ushort* __restrict__ t0h) {
    __shared__ float Wl[64 * HD];       // 32 KB
    __shared__ float hl[32 * HD];       // 16 KB
    __shared__ float sCW[2 * HD], sCB[HD], sLG[HD], sLB[HD];
    int t = threadIdx.x;
    sCW[t] = cp[O_CW + t];
    if (t < 128) { sCB[t] = cp[O_CB + t]; sLG[t] = cp[O_LNG + t]; sLB[t] = cp[O_LNB + t]; }
    __syncthreads();
    int nodeBase = blockIdx.x * 32;
    const float* X = cp + O_X;
    float4* hl4 = (float4*)hl;
#pragma unroll
    for (int r = 0; r < 4; r++) {
        int idx = r * 256 + t;
        int n = nodeBase + (idx >> 5);
        int c4 = idx & 31;
        int f = c4 * 4;
        float4 u = make_float4(0.f, 0.f, 0.f, 0.f);
        if (n < NN) {
            float x0 = X[n * 2], x1 = X[n * 2 + 1];
            u.x = fmaxf(0.f, x0 * sCW[f]     + x1 * sCW[HD + f]     + sCB[f]);
            u.y = fmaxf(0.f, x0 * sCW[f + 1] + x1 * sCW[HD + f + 1] + sCB[f + 1]);
            u.z = fmaxf(0.f, x0 * sCW[f + 2] + x1 * sCW[HD + f + 2] + sCB[f + 2]);
            u.w = fmaxf(0.f, x0 * sCW[f + 3] + x1 * sCW[HD + f + 3] + sCB[f + 3]);
        }
        float s = u.x + u.y + u.z + u.w;
        float q = u.x * u.x + u.y * u.y + u.z * u.z + u.w * u.w;
        for (int o = 16; o; o >>= 1) { s += __shfl_xor(s, o); q += __shfl_xor(q, o); }
        float m = s * (1.f / HD);
        float var = q * (1.f / HD) - m * m;
        float rr = rsqrtf(var + EPSN);
        u.x = (u.x - m) * rr * sLG[f]     + sLB[f];
        u.y = (u.y - m) * rr * sLG[f + 1] + sLB[f + 1];
        u.z = (u.z - m) * rr * sLG[f + 2] + sLB[f + 2];
        u.w = (u.w - m) * rr * sLG[f + 3] + sLB[f + 3];
        hl4[idx] = u;
        if (n < NN) ((ushort4*)(hh + (size_t)n * HD))[c4] = f4toh4(u);
    }
    int fq = t & 31;
    int ng = t >> 5;
    float4 acc[4];
#pragma unroll
    for (int j = 0; j < 4; j++) acc[j] = make_float4(0.f, 0.f, 0.f, 0.f);
    const float4* Wl4 = (const float4*)Wl;
    for (int ph = 0; ph < 2; ph++) {
        __syncthreads();
        const float4* Wg4 = (const float4*)(Wf + ph * 64 * HD);
        float4* Wld = (float4*)Wl;
#pragma unroll
        for (int r = 0; r < 8; r++) Wld[r * 256 + t] = Wg4[r * 256 + t];
        __syncthreads();
        for (int k4 = 0; k4 < 16; k4++) {
            int kb = k4 * 4;
            float4 w0 = Wl4[(kb + 0) * 32 + fq];
            float4 w1 = Wl4[(kb + 1) * 32 + fq];
            float4 w2 = Wl4[(kb + 2) * 32 + fq];
            float4 w3 = Wl4[(kb + 3) * 32 + fq];
#pragma unroll
            for (int j = 0; j < 4; j++) {
                float4 hv = hl4[(ng + 8 * j) * 32 + ph * 16 + k4];
                acc[j].x += hv.x * w0.x + hv.y * w1.x + hv.z * w2.x + hv.w * w3.x;
                acc[j].y += hv.x * w0.y + hv.y * w1.y + hv.z * w2.y + hv.w * w3.y;
                acc[j].z += hv.x * w0.z + hv.y * w1.z + hv.z * w2.z + hv.w * w3.z;
                acc[j].w += hv.x * w0.w + hv.y * w1.w + hv.z * w2.w + hv.w * w3.w;
            }
        }
    }
#pragma unroll
    for (int j = 0; j < 4; j++) {
        int n = nodeBase + ng + 8 * j;
        if (n < NN) ((ushort4*)(t0h + (size_t)n * HD))[fq] = f4toh4(acc[j]);
    }
}

// ------- fused BN+residual+InstanceNorm + GEMM (layers 1,2); agg & h fp16 -------

__global__ __launch_bounds__(256) void k_gemm_fused(const ushort* __restrict__ aggh,
                                                    const float* __restrict__ stats,
                                                    const float* __restrict__ bias,
                                                    const float* __restrict__ bng,
                                                    const float* __restrict__ bnb,
                                                    ushort* __restrict__ hh,
                                                    const float* __restrict__ Wf,
                                                    ushort* __restrict__ t0h) {
    __shared__ float Wl[64 * HD];       // 32 KB
    __shared__ float hl[32 * HD];       // 16 KB
    __shared__ float scL[HD], shL[HD], bL[HD];
    int t = threadIdx.x;
    if (t < 128) {
        const float invN = 1.f / NN;
        float m = stats[t] * invN;
        float v = stats[128 + t] * invN - m * m;
        float sc = bng[t] * rsqrtf(v + EPSN);
        scL[t] = sc;
        shL[t] = bnb[t] - m * sc;
        bL[t] = bias[t];
    }
    __syncthreads();
    int nodeBase = blockIdx.x * 32;
    const ushort4* a4 = (const ushort4*)aggh;
    float4* hl4 = (float4*)hl;
#pragma unroll
    for (int r = 0; r < 4; r++) {
        int idx = r * 256 + t;
        int n = nodeBase + (idx >> 5);
        int c4 = idx & 31;
        float4 u = make_float4(0.f, 0.f, 0.f, 0.f);
        if (n < NN) {
            float4 av = h4tof4(a4[(size_t)n * 32 + c4]);
            float4 hv = h4tof4(((const ushort4*)(hh + (size_t)n * HD))[c4]);
            int f = c4 * 4;
            float y0 = fmaxf(0.f, av.x + bL[f]);
            float y1 = fmaxf(0.f, av.y + bL[f + 1]);
            float y2 = fmaxf(0.f, av.z + bL[f + 2]);
            float y3 = fmaxf(0.f, av.w + bL[f + 3]);
            u.x = y0 * scL[f]     + shL[f]     + hv.x;
            u.y = y1 * scL[f + 1] + shL[f + 1] + hv.y;
            u.z = y2 * scL[f + 2] + shL[f + 2] + hv.z;
            u.w = y3 * scL[f + 3] + shL[f + 3] + hv.w;
        }
        float s = u.x + u.y + u.z + u.w;
        float q = u.x * u.x + u.y * u.y + u.z * u.z + u.w * u.w;
        for (int o = 16; o; o >>= 1) { s += __shfl_xor(s, o); q += __shfl_xor(q, o); }
        float m = s * (1.f / HD);
        float var = q * (1.f / HD) - m * m;
        float rr = rsqrtf(var + EPSN);
        u.x = (u.x - m) * rr; u.y = (u.y - m) * rr;
        u.z = (u.z - m) * rr; u.w = (u.w - m) * rr;
        hl4[idx] = u;
        if (n < NN) ((ushort4*)(hh + (size_t)n * HD))[c4] = f4toh4(u);
    }
    int fq = t & 31;
    int ng = t >> 5;
    float4 acc[4];
#pragma unroll
    for (int j = 0; j < 4; j++) acc[j] = make_float4(0.f, 0.f, 0.f, 0.f);
    const float4* Wl4 = (const float4*)Wl;
    for (int ph = 0; ph < 2; ph++) {
        __syncthreads();
        const float4* Wg4 = (const float4*)(Wf + ph * 64 * HD);
        float4* Wld = (float4*)Wl;
#pragma unroll
        for (int r = 0; r < 8; r++) Wld[r * 256 + t] = Wg4[r * 256 + t];
        __syncthreads();
        for (int k4 = 0; k4 < 16; k4++) {
            int kb = k4 * 4;
            float4 w0 = Wl4[(kb + 0) * 32 + fq];
            float4 w1 = Wl4[(kb + 1) * 32 + fq];
            float4 w2 = Wl4[(kb + 2) * 32 + fq];
            float4 w3 = Wl4[(kb + 3) * 32 + fq];
#pragma unroll
            for (int j = 0; j < 4; j++) {
                float4 hv = hl4[(ng + 8 * j) * 32 + ph * 16 + k4];
                acc[j].x += hv.x * w0.x + hv.y * w1.x + hv.z * w2.x + hv.w * w3.x;
                acc[j].y += hv.x * w0.y + hv.y * w1.y + hv.z * w2.y + hv.w * w3.y;
                acc[j].z += hv.x * w0.z + hv.y * w1.z + hv.z * w2.z + hv.w * w3.z;
                acc[j].w += hv.x * w0.w + hv.y * w1.w + hv.z * w2.w + hv.w * w3.w;
            }
        }
    }
#pragma unroll
    for (int j = 0; j < 4; j++) {
        int n = nodeBase + ng + 8 * j;
        if (n < NN) ((ushort4*)(t0h + (size_t)n * HD))[fq] = f4toh4(acc[j]);
    }
}

// ------- aggregate (round-9 structure): static grid-stride, barrier-free,
// padded tail-free CSR, software-pipelined gathers; agg stored fp16 -------

__global__ __launch_bounds__(256) void k_agg(const ushort* __restrict__ t0h,
                                             const int2* __restrict__ srw,
                                             const int* __restrict__ startA,
                                             const int* __restrict__ deg,
                                             const float* __restrict__ dinv,
                                             const float* __restrict__ bias,
                                             ushort* __restrict__ aggh,
                                             float* __restrict__ stats) {
    int t = threadIdx.x;
    int f = t & 127;
    int half = t >> 7;
    float bs = bias[f];
    float rs1 = 0.f, rs2 = 0.f;
    for (int pair = blockIdx.x; pair * 2 < NN; pair += gridDim.x) {
        int i = pair * 2 + half;
        if (i < NN) {
            int s = startA[i];
            int cnt = deg[i];                 // edge-only count
            int nb = (cnt + 7) & ~7;          // padded batch count (sentinels w=0)
            int2 e[8];
            if (nb > 0) {
#pragma unroll
                for (int u = 0; u < 8; u++) e[u] = srw[s + u];
            }
            float di = dinv[i];
            float acc = di * di * h2f(t0h[i * HD + f]);   // self-loop term
            float a[8];
#pragma unroll
            for (int u = 0; u < 8; u++) a[u] = 0.f;
            for (int j = 0; j < nb; j += 8) {
                float g[8];
#pragma unroll
                for (int u = 0; u < 8; u++) g[u] = h2f(t0h[e[u].x + f]);   // gathers first
                int2 en[8];
                if (j + 8 < nb) {
#pragma unroll
                    for (int u = 0; u < 8; u++) en[u] = srw[s + j + 8 + u]; // prefetch next
                }
#pragma unroll
                for (int u = 0; u < 8; u++) a[u] += __int_as_float(e[u].y) * g[u];
                if (j + 8 < nb) {
#pragma unroll
                    for (int u = 0; u < 8; u++) e[u] = en[u];
                }
            }
            acc += ((a[0] + a[1]) + (a[2] + a[3])) + ((a[4] + a[5]) + (a[6] + a[7]));
            ushort au = f2h(acc);
            aggh[(size_t)i * HD + f] = au;
            float y = fmaxf(0.f, h2f(au) + bs);   // rounded value = what consumers see
            rs1 += y;
            rs2 += y * y;
        }
    }
    __shared__ float l1[256], l2[256];
    l1[t] = rs1; l2[t] = rs2;
    __syncthreads();
    if (t < 128) {
        atomicAdd(&stats[t], l1[t] + l1[t + 128]);
        atomicAdd(&stats[128 + t], l2[t] + l2[t + 128]);
    }
}

// ------- fused layer-3 post + MLP head: u = IN(BN(relu(agg+b)) + h) in LDS,
// then out = tanh(relu(u@fc1+b1)@fc2+b2). h is dead after -> never written. -------

__global__ __launch_bounds__(256) void k_post_head(const ushort* __restrict__ aggh,
                                                   const float* __restrict__ stats,
                                                   const float* __restrict__ bias,
                                                   const float* __restrict__ bng,
                                                   const float* __restrict__ bnb,
                                                   const ushort* __restrict__ hh,
                                                   const float* __restrict__ cp,
                                                   const int* __restrict__ flags,
                                                   void* __restrict__ outv) {
    __shared__ float hl[32 * HD];       // 16 KB (u rows)
    __shared__ float W1[HD * 32];       // 16 KB fc1
    __shared__ float scL[HD], shL[HD], bL[HD];
    __shared__ float B1s[32], W2s[64], B2s[2];
    int t = threadIdx.x;
    if (t < 128) {
        const float invN = 1.f / NN;
        float m = stats[t] * invN;
        float v = stats[128 + t] * invN - m * m;
        float sc = bng[t] * rsqrtf(v + EPSN);
        scL[t] = sc;
        shL[t] = bnb[t] - m * sc;
        bL[t] = bias[t];
    }
    const float* f1W = cp + O_F1W;
    for (int r = 0; r < 16; r++) W1[r * 256 + t] = f1W[r * 256 + t];
    if (t < 32) B1s[t] = cp[O_F1B + t];
    if (t < 64) W2s[t] = cp[O_F2W + t];
    if (t < 2) B2s[t] = cp[O_F2B + t];
    __syncthreads();
    int nodeBase = blockIdx.x * 32;
    const ushort4* a4 = (const ushort4*)aggh;
    float4* hl4 = (float4*)hl;
#pragma unroll
    for (int r = 0; r < 4; r++) {
        int idx = r * 256 + t;
        int n = nodeBase + (idx >> 5);
        int c4 = idx & 31;
        float4 u = make_float4(0.f, 0.f, 0.f, 0.f);
        if (n < NN) {
            float4 av = h4tof4(a4[(size_t)n * 32 + c4]);
            float4 hv = h4tof4(((const ushort4*)(hh + (size_t)n * HD))[c4]);
            int f = c4 * 4;
            float y0 = fmaxf(0.f, av.x + bL[f]);
            float y1 = fmaxf(0.f, av.y + bL[f + 1]);
            float y2 = fmaxf(0.f, av.z + bL[f + 2]);
            float y3 = fmaxf(0.f, av.w + bL[f + 3]);
            u.x = y0 * scL[f]     + shL[f]     + hv.x;
            u.y = y1 * scL[f + 1] + shL[f + 1] + hv.y;
            u.z = y2 * scL[f + 2] + shL[f + 2] + hv.z;
            u.w = y3 * scL[f + 3] + shL[f + 3] + hv.w;
        }
        float s = u.x + u.y + u.z + u.w;
        float q = u.x * u.x + u.y * u.y + u.z * u.z + u.w * u.w;
        for (int o = 16; o; o >>= 1) { s += __shfl_xor(s, o); q += __shfl_xor(q, o); }
        float m = s * (1.f / HD);
        float var = q * (1.f / HD) - m * m;
        float rr = rsqrtf(var + EPSN);
        u.x = (u.x - m) * rr; u.y = (u.y - m) * rr;
        u.z = (u.z - m) * rr; u.w = (u.w - m) * rr;
        hl4[idx] = u;
    }
    __syncthreads();
    // head: 8 threads per node; each thread 4 fc1 outputs
    int node = t >> 3;              // 0..31
    int o4 = (t & 7) * 4;           // fc1 output quad base
    const float* ur = hl + node * HD;
    float a0 = B1s[o4], a1 = B1s[o4 + 1], a2 = B1s[o4 + 2], a3 = B1s[o4 + 3];
    for (int k = 0; k < HD; k++) {
        float uv = ur[k];
        float4 w = ((const float4*)(W1 + k * 32))[t & 7];
        a0 += uv * w.x; a1 += uv * w.y; a2 += uv * w.z; a3 += uv * w.w;
    }
    a0 = fmaxf(0.f, a0); a1 = fmaxf(0.f, a1);
    a2 = fmaxf(0.f, a2); a3 = fmaxf(0.f, a3);
    float o0 = a0 * W2s[o4 * 2]     + a1 * W2s[(o4 + 1) * 2]
             + a2 * W2s[(o4 + 2) * 2] + a3 * W2s[(o4 + 3) * 2];
    float o1 = a0 * W2s[o4 * 2 + 1]     + a1 * W2s[(o4 + 1) * 2 + 1]
             + a2 * W2s[(o4 + 2) * 2 + 1] + a3 * W2s[(o4 + 3) * 2 + 1];
    for (int o = 1; o < 8; o <<= 1) { o0 += __shfl_xor(o0, o); o1 += __shfl_xor(o1, o); }
    int n = nodeBase + node;
    if ((t & 7) == 0 && n < NN) {
        o0 = tanhf(o0 + B2s[0]);
        o1 = tanhf(o1 + B2s[1]);
        if (flags[1]) {
            ushort* ob = (ushort*)outv;
            ob[n * 2] = f2us(o0);
            ob[n * 2 + 1] = f2us(o1);
        } else {
            float* of = (float*)outv;
            of[n * 2] = o0;
            of[n * 2 + 1] = o1;
        }
    }
}

// ---------------- launch ----------------

extern "C" void kernel_launch(void* const* d_in, const int* in_sizes, int n_in,
                              void* d_out, int out_size, void* d_ws, size_t ws_size,
                              hipStream_t stream) {
    const int* ei = (const int*)d_in[1];

    Ptrs ptrs;
    ptrs.p[0] = d_in[0];                                  // x
    for (int s = 1; s < 17; s++) ptrs.p[s] = d_in[s + 1]; // coord_W .. fc2_b

    char* wsp = (char*)d_ws;
    size_t off = 0;
    auto alloc = [&](size_t bytes) {
        void* p = wsp + off;
        off += (bytes + 255) & ~(size_t)255;
        return p;
    };
    float* cp     = (float*)alloc((size_t)O_TOT * 4);       // 0.62 MB canonical fp32 params
    ushort* hh    = (ushort*)alloc((size_t)NN * HD * 2);    // 12.8 MB fp16 residual
    ushort* t0h   = (ushort*)alloc((size_t)NN * HD * 2);    // 12.8 MB fp16
    ushort* aggh  = (ushort*)alloc((size_t)NN * HD * 2);    // 12.8 MB fp16
    int* zr       = (int*)alloc((size_t)(NN + 768 + 64) * 4); // zeroed region
    float* dinv   = (float*)alloc((size_t)NN * 4);
    int2* srw     = (int2*)alloc((size_t)CAP * 8);          // 9.2 MB padded CSR
    int* startA   = (int*)alloc((size_t)NN * 4);
    int* curA     = (int*)alloc((size_t)NN * 4);

    int* deg     = zr;                      // NN ints (edge-only in-degree)
    float* stats = (float*)(zr + NN);       // 768 floats (3 layers x 256)
    int* misc    = zr + NN + 768;           // [0]=alloc cursor, [8..9]=flags
    int* flags   = misc + 8;

    const int BN_NODE = (NN + 255) / 256;   // 196
    const int BN_EDGE = (NE + 255) / 256;   // 3125
    const int BN_CONV = (O_TOT + 255) / 256;
    const int BN_G32  = (NN + 31) / 32;     // 1563

    const float* W[3] = {cp + O_W1, cp + O_W2, cp + O_W3};
    const float* B[3] = {cp + O_B1, cp + O_B2, cp + O_B3};

    hipMemsetAsync(zr, 0, (size_t)(NN + 768 + 64) * 4, stream);
    k_conv<<<BN_CONV, 256, 0, stream>>>(ptrs, ei, (const ushort*)d_in[2], cp, flags);
    k_deg<<<BN_EDGE, 256, 0, stream>>>(ei, flags, deg);
    k_dinv_alloc<<<BN_NODE, 256, 0, stream>>>(deg, dinv, startA, curA, misc, srw);
    k_fill<<<BN_EDGE, 256, 0, stream>>>(ei, flags, dinv, curA, srw);

    k_gemm0<<<BN_G32, 256, 0, stream>>>(cp, hh, W[0], t0h);
    k_agg<<<2048, 256, 0, stream>>>(t0h, srw, startA, deg, dinv, B[0], aggh, stats);
    for (int l = 1; l < 3; l++) {
        k_gemm_fused<<<BN_G32, 256, 0, stream>>>(aggh, stats + 256 * (l - 1),
                                                 B[l - 1], cp + O_BNG, cp + O_BNB,
                                                 hh, W[l], t0h);
        k_agg<<<2048, 256, 0, stream>>>(t0h, srw, startA, deg, dinv, B[l],
                                        aggh, stats + 256 * l);
    }
    k_post_head<<<BN_G32, 256, 0, stream>>>(aggh, stats + 512, B[2], cp + O_BNG,
                                            cp + O_BNB, hh, cp, flags, d_out);
}